// Round 3
// baseline (253.342 us; speedup 1.0000x reference)
//
#include <hip/hip_runtime.h>
#include <math.h>

#define NZ    128
#define H1    512
#define H2    1024
#define IMG   784
#define IMGP  832     // layer-3 N padded to 13*64
#define BATCH 4096
#define NGEN  10
#define MPAD  128     // packed-row slack so tail tiles can stage past ng

typedef _Float16 f16;
typedef __attribute__((ext_vector_type(8))) _Float16 half8;
typedef __attribute__((ext_vector_type(4))) float floatx4;

// transpose tile counts (64x64 tiles) for the fused prep kernel
#define TB1 ((NZ / 64) * (H1 / 64) * NGEN)    // 160
#define TB2 ((H1 / 64) * (H2 / 64) * NGEN)    // 1280
#define TB3 ((H2 / 64) * (IMGP / 64) * NGEN)  // 2080

__device__ __forceinline__ void cp16(void* l, const void* g) {
    __builtin_amdgcn_global_load_lds((const __attribute__((address_space(1))) void*)g,
                                     (__attribute__((address_space(3))) void*)l, 16, 0, 0);
}

// ---------------- transpose one 64x64 tile: W [g][K][N] f32 -> Wt [g][NPAD][K] f16 ----------------
template<int K, int N, int NPAD>
__device__ __forceinline__ void t_tile(int idx, const float* __restrict__ W,
                                       f16* __restrict__ Wt, f16 (*L)[72]) {
    constexpr int KT = K / 64, NT = NPAD / 64;
    const int g  = idx / (KT * NT);
    const int r2 = idx % (KT * NT);
    const int k0 = (r2 % KT) * 64;
    const int n0 = (r2 / KT) * 64;
    const int t = threadIdx.x;
    {
        const int kk0 = t >> 4;            // 0..15
        const int nq  = (t & 15) * 4;      // 0..60
        #pragma unroll
        for (int it = 0; it < 4; ++it) {
            const int kk = kk0 + it * 16;
            float4 v = make_float4(0.f, 0.f, 0.f, 0.f);
            if (n0 + nq < N)               // N % 4 == 0: quads never straddle
                v = *(const float4*)(W + ((size_t)g * K + (k0 + kk)) * N + n0 + nq);
            L[nq + 0][kk] = (f16)v.x;
            L[nq + 1][kk] = (f16)v.y;
            L[nq + 2][kk] = (f16)v.z;
            L[nq + 3][kk] = (f16)v.w;
        }
    }
    __syncthreads();
    {
        const int nn0 = t >> 3;            // 0..31
        const int kq  = (t & 7) * 8;       // 0..56
        #pragma unroll
        for (int it = 0; it < 2; ++it) {
            const int nn = nn0 + it * 32;
            *(half8*)(Wt + ((size_t)g * NPAD + (n0 + nn)) * K + k0 + kq) =
                *(const half8*)&L[nn][kq];
        }
    }
}

// ---------------- fused prep: block 0 = hist+perm, rest = weight transposes ----------------
__global__ __launch_bounds__(256)
void prep(const float* __restrict__ W1, const float* __restrict__ W2,
          const float* __restrict__ W3, f16* __restrict__ W1t,
          f16* __restrict__ W2t, f16* __restrict__ W3t,
          const int* __restrict__ g_idx, int* __restrict__ seg,
          int* __restrict__ perm) {
    __shared__ f16 L[64][72];
    __shared__ int lc[NGEN];
    __shared__ int lb[NGEN + 1];
    int bid = blockIdx.x;
    if (bid == 0) {
        const int t = threadIdx.x;
        if (t < NGEN) lc[t] = 0;
        __syncthreads();
        int gv[BATCH / 256];
        #pragma unroll
        for (int i = 0; i < BATCH / 256; ++i) {
            gv[i] = g_idx[t + i * 256];
            atomicAdd(&lc[gv[i]], 1);
        }
        __syncthreads();
        if (t == 0) {
            int s = 0;
            for (int g = 0; g < NGEN; ++g) { lb[g] = s; s += lc[g]; }
            lb[NGEN] = s;
        }
        __syncthreads();
        if (t <= NGEN) seg[t] = lb[t];
        if (t < NGEN) lc[t] = lb[t];      // reuse as cursors
        __syncthreads();
        #pragma unroll
        for (int i = 0; i < BATCH / 256; ++i) {
            int p = atomicAdd(&lc[gv[i]], 1);
            perm[p] = t + i * 256;
        }
        return;
    }
    --bid;
    if (bid < TB1) { t_tile<NZ, H1, H1>(bid, W1, W1t, L); return; }
    bid -= TB1;
    if (bid < TB2) { t_tile<H1, H2, H2>(bid, W2, W2t, L); return; }
    bid -= TB2;
    t_tile<H2, IMG, IMGP>(bid, W3, W3t, L);
}

// ---------------- 64x64-tile grouped GEMM, A-direct-to-register ----------------
// Block = (m-tile 64, n-tile 64, gen), 4 waves 2x2, each wave 32x32 (acc[2][2]).
// A is NOT staged in LDS: each lane loads its own MFMA A-fragment straight
// from global (16B at row*K + quad*8; 4-lane lq-groups cover full 64B lines).
// LDS holds only B: 2 x 8 KB double-buffer = 16 KB/block -> high block/CU
// ceiling; grid at n-tile 64 gives ~4 active blocks/CU (vs 1.9 before) so
// cross-block TLP covers the per-step barrier drain.
// Per K-step per wave: 2 cp16 (B) + 4 reg-loads (A, next step) + 4 ds_read
// + 8 MFMA, ONE __syncthreads. The drain at the barrier COMPLETES the
// next-step A/B prefetch instead of discarding it.
// B LDS XOR-swizzle: phys k-quad = logical ^ ((row>>1)&7) (2-way = free).
// B col map: frag nf -> col wn + 2*lm + nf: adjacent col pairs per lane.
// ACT: 0 relu, 1 tanh. SCATTER: 0 -> packed f16 Ch; 1 -> f32 out via perm.
// GATHER: 1 -> A fragments from f32 z via perm with in-register convert.
template<int K, int NOUT, int NPADB, int ACT, int SCATTER, int GATHER>
__global__ __launch_bounds__(256)
void gemm(const f16* __restrict__ Ap, const float* __restrict__ Az,
          const f16* __restrict__ Wt, const float* __restrict__ bias,
          f16* __restrict__ Ch, float* __restrict__ Cout,
          const int* __restrict__ seg, const int* __restrict__ perm) {
    const int g  = blockIdx.z;
    const int s0 = seg[g];
    const int ng = seg[g + 1] - s0;
    const int m0 = blockIdx.x * 64;
    if (m0 >= ng) return;                 // block-uniform early exit
    const int n0 = blockIdx.y * 64;

    __shared__ f16 Bs[2][64 * 64];        // 16 KB total

    const int tid = threadIdx.x, lane = tid & 63, w = tid >> 6;

    // B staging: wave w stages rows [w*16, w*16+16), 2 cp16.
    const f16* gb[2]; int lbo[2];
    #pragma unroll
    for (int j = 0; j < 2; ++j) {
        const int r   = w * 16 + j * 8 + (lane >> 3);
        const int swz = ((lane & 7) ^ ((r >> 1) & 7)) * 8;
        gb[j]  = Wt + ((size_t)g * NPADB + n0 + r) * K + swz;
        lbo[j] = (w * 16 + j * 8) * 64;
    }

    const int wm = (w & 1) * 32, wn = (w >> 1) * 32;
    const int lm = lane & 15, lq = lane >> 4;

    // A-fragment global pointers, one per mt: lane reads 16B (half8) at
    // row (wm + mt*16 + lm), k-quad (ks*4 + lq). Tail rows (>= ng) read
    // in-bounds slack (h*p buffers have MPAD rows; z via clamped perm).
    const f16*  gA[2];
    const float* gz[2];
    #pragma unroll
    for (int mt = 0; mt < 2; ++mt) {
        const int row = wm + mt * 16 + lm;
        if constexpr (GATHER != 0) {
            const int pr = min(s0 + m0 + row, BATCH - 1);
            gz[mt] = Az + (size_t)perm[pr] * K + lq * 8;
        } else {
            gA[mt] = Ap + (size_t)(s0 + m0 + row) * K + lq * 8;
        }
    }

    floatx4 acc[2][2] = {};
    constexpr int NT = K / 64;
    half8 areg[2][2][2];                  // [phase][mt][ks] — static-indexed

    // prologue: stage B tile 0 + load A tile 0
    #pragma unroll
    for (int j = 0; j < 2; ++j) { cp16(&Bs[0][lbo[j]], gb[j]); gb[j] += 64; }
    #pragma unroll
    for (int mt = 0; mt < 2; ++mt)
        #pragma unroll
        for (int ks = 0; ks < 2; ++ks) {
            if constexpr (GATHER != 0) {
                const float4 v0 = *(const float4*)(gz[mt] + ks * 32);
                const float4 v1 = *(const float4*)(gz[mt] + ks * 32 + 4);
                half8 h;
                h[0] = (f16)v0.x; h[1] = (f16)v0.y; h[2] = (f16)v0.z; h[3] = (f16)v0.w;
                h[4] = (f16)v1.x; h[5] = (f16)v1.y; h[6] = (f16)v1.z; h[7] = (f16)v1.w;
                areg[0][mt][ks] = h;
            } else {
                areg[0][mt][ks] = *(const half8*)(gA[mt] + ks * 32);
            }
        }
    if constexpr (GATHER != 0) { gz[0] += 64; gz[1] += 64; }
    else                       { gA[0] += 64; gA[1] += 64; }
    __syncthreads();                      // drains vmcnt: tile 0 ready

    #pragma unroll
    for (int kc = 0; kc < NT; ++kc) {
        const int cur = kc & 1;
        if (kc + 1 < NT) {
            // issue next-tile B staging + A reg-loads BEFORE compute:
            // latency overlaps MFMA, completes at the end-of-step barrier
            #pragma unroll
            for (int j = 0; j < 2; ++j) { cp16(&Bs[cur ^ 1][lbo[j]], gb[j]); gb[j] += 64; }
            #pragma unroll
            for (int mt = 0; mt < 2; ++mt)
                #pragma unroll
                for (int ks = 0; ks < 2; ++ks) {
                    if constexpr (GATHER != 0) {
                        const float4 v0 = *(const float4*)(gz[mt] + ks * 32);
                        const float4 v1 = *(const float4*)(gz[mt] + ks * 32 + 4);
                        half8 h;
                        h[0] = (f16)v0.x; h[1] = (f16)v0.y; h[2] = (f16)v0.z; h[3] = (f16)v0.w;
                        h[4] = (f16)v1.x; h[5] = (f16)v1.y; h[6] = (f16)v1.z; h[7] = (f16)v1.w;
                        areg[cur ^ 1][mt][ks] = h;
                    } else {
                        areg[cur ^ 1][mt][ks] = *(const half8*)(gA[mt] + ks * 32);
                    }
                }
            if constexpr (GATHER != 0) { gz[0] += 64; gz[1] += 64; }
            else                       { gA[0] += 64; gA[1] += 64; }
        }
        // compute tile kc: B from Bs[cur], A from areg[cur]
        #pragma unroll
        for (int ks = 0; ks < 2; ++ks) {
            half8 b[2];
            #pragma unroll
            for (int nf = 0; nf < 2; ++nf) {
                const int r  = wn + 2 * lm + nf;
                const int pq = (ks * 4 + lq) ^ ((r >> 1) & 7);
                b[nf] = *(const half8*)&Bs[cur][r * 64 + pq * 8];
            }
            #pragma unroll
            for (int mt = 0; mt < 2; ++mt)
                #pragma unroll
                for (int nf = 0; nf < 2; ++nf)
                    acc[mt][nf] = __builtin_amdgcn_mfma_f32_16x16x32_f16(
                        areg[cur][mt][ks], b[nf], acc[mt][nf], 0, 0, 0);
        }
        if (kc + 1 < NT) __syncthreads(); // next tile staged; Bs[cur] reads done
    }

    // epilogue: C/D row = (lane>>4)*4 + reg; cols c, c+1 (nf=0,1).
    // Even c: pair never straddles NOUT.
    const int c = n0 + wn + 2 * lm;
    const bool in0 = (!SCATTER) || (c < NOUT);
    const float b0 = in0 ? bias[(size_t)g * NOUT + c]     : 0.f;
    const float b1 = in0 ? bias[(size_t)g * NOUT + c + 1] : 0.f;
    #pragma unroll
    for (int mt = 0; mt < 2; ++mt)
        #pragma unroll
        for (int rr = 0; rr < 4; ++rr) {
            const int gr = m0 + wm + mt * 16 + lq * 4 + rr;
            if (gr >= ng) continue;
            float x0 = acc[mt][0][rr] + b0;
            float x1 = acc[mt][1][rr] + b1;
            if (ACT == 0) {
                x0 = fmaxf(x0, 0.f); x1 = fmaxf(x1, 0.f);
            } else {                       // tanh, inf-safe
                const float e0 = __expf(2.f * x0);
                const float e1 = __expf(2.f * x1);
                x0 = 1.f - 2.f / (e0 + 1.f);
                x1 = 1.f - 2.f / (e1 + 1.f);
            }
            if (SCATTER) {
                if (in0) {
                    const size_t orow = (size_t)perm[s0 + gr];
                    *(float2*)&Cout[orow * NOUT + c] = make_float2(x0, x1);
                }
            } else {
                union { uint u; f16 h[2]; } o;
                o.h[0] = (f16)x0; o.h[1] = (f16)x1;
                *(uint*)&Ch[(size_t)(s0 + gr) * NOUT + c] = o.u;
            }
        }
}

extern "C" void kernel_launch(void* const* d_in, const int* in_sizes, int n_in,
                              void* d_out, int out_size, void* d_ws, size_t ws_size,
                              hipStream_t stream) {
    const float* z    = (const float*)d_in[0];
    const int*   gidx = (const int*)  d_in[1];
    const float* W1   = (const float*)d_in[2];
    const float* b1   = (const float*)d_in[3];
    const float* W2   = (const float*)d_in[4];
    const float* b2   = (const float*)d_in[5];
    const float* W3   = (const float*)d_in[6];
    const float* b3   = (const float*)d_in[7];
    float* out = (float*)d_out;

    char* ws = (char*)d_ws;
    size_t off = 0;
    auto alloc = [&](size_t bytes) { size_t o = off; off = (off + bytes + 255) & ~255ULL; return o; };
    int* seg  = (int*)(ws + alloc((size_t)(NGEN + 1) * 4));
    int* perm = (int*)(ws + alloc((size_t)(BATCH + MPAD) * 4));
    f16* h1p = (f16*)(ws + alloc((size_t)(BATCH + MPAD) * H1 * 2));
    f16* h2p = (f16*)(ws + alloc((size_t)(BATCH + MPAD) * H2 * 2));
    f16* W1t = (f16*)(ws + alloc((size_t)NGEN * H1 * NZ * 2));
    f16* W2t = (f16*)(ws + alloc((size_t)NGEN * H2 * H1 * 2));
    f16* W3t = (f16*)(ws + alloc((size_t)NGEN * IMGP * H2 * 2));

    // K1: hist (1 block) co-scheduled with all weight transposes
    prep<<<dim3(1 + TB1 + TB2 + TB3), dim3(256), 0, stream>>>(
        W1, W2, W3, W1t, W2t, W3t, gidx, seg, perm);

    // grid.x = 16 covers any plausible bucket size (<=1024); empty m-tiles
    // exit on the seg[] read. Active blocks/CU ~ 2.2 / 4.4 / 3.6.
    gemm<NZ, H1, H1, 0, 0, 1><<<dim3(16, H1 / 64, NGEN), dim3(256), 0, stream>>>(
        nullptr, z, W1t, b1, h1p, nullptr, seg, perm);
    gemm<H1, H2, H2, 0, 0, 0><<<dim3(16, H2 / 64, NGEN), dim3(256), 0, stream>>>(
        h1p, nullptr, W2t, b2, h2p, nullptr, seg, perm);
    gemm<H2, IMG, IMGP, 1, 1, 0><<<dim3(16, IMGP / 64, NGEN), dim3(256), 0, stream>>>(
        h2p, nullptr, W3t, b3, nullptr, out, seg, perm);
}

// Round 4
// 186.873 us; speedup vs baseline: 1.3557x; 1.3557x over previous
//
#include <hip/hip_runtime.h>
#include <math.h>

#define NZ    128
#define H1    512
#define H2    1024
#define IMG   784
#define IMGP  832     // layer-3 N padded to 13*64
#define BATCH 4096
#define NGEN  10
#define MPAD  128     // packed-row slack so tail tiles can stage past ng

typedef _Float16 f16;
typedef __attribute__((ext_vector_type(8))) _Float16 half8;
typedef __attribute__((ext_vector_type(4))) float floatx4;

// transpose tile counts (64x64 tiles) for the fused prep kernel
#define TB1 ((NZ / 64) * (H1 / 64) * NGEN)    // 160
#define TB2 ((H1 / 64) * (H2 / 64) * NGEN)    // 1280
#define TB3 ((H2 / 64) * (IMGP / 64) * NGEN)  // 2080

__device__ __forceinline__ void cp16(void* l, const void* g) {
    __builtin_amdgcn_global_load_lds((const __attribute__((address_space(1))) void*)g,
                                     (__attribute__((address_space(3))) void*)l, 16, 0, 0);
}

// ---------------- transpose one 64x64 tile: W [g][K][N] f32 -> Wt [g][NPAD][K] f16 ----------------
template<int K, int N, int NPAD>
__device__ __forceinline__ void t_tile(int idx, const float* __restrict__ W,
                                       f16* __restrict__ Wt, f16 (*L)[72]) {
    constexpr int KT = K / 64, NT = NPAD / 64;
    const int g  = idx / (KT * NT);
    const int r2 = idx % (KT * NT);
    const int k0 = (r2 % KT) * 64;
    const int n0 = (r2 / KT) * 64;
    const int t = threadIdx.x;
    {
        const int kk0 = t >> 4;            // 0..15
        const int nq  = (t & 15) * 4;      // 0..60
        #pragma unroll
        for (int it = 0; it < 4; ++it) {
            const int kk = kk0 + it * 16;
            float4 v = make_float4(0.f, 0.f, 0.f, 0.f);
            if (n0 + nq < N)               // N % 4 == 0: quads never straddle
                v = *(const float4*)(W + ((size_t)g * K + (k0 + kk)) * N + n0 + nq);
            L[nq + 0][kk] = (f16)v.x;
            L[nq + 1][kk] = (f16)v.y;
            L[nq + 2][kk] = (f16)v.z;
            L[nq + 3][kk] = (f16)v.w;
        }
    }
    __syncthreads();
    {
        const int nn0 = t >> 3;            // 0..31
        const int kq  = (t & 7) * 8;       // 0..56
        #pragma unroll
        for (int it = 0; it < 2; ++it) {
            const int nn = nn0 + it * 32;
            *(half8*)(Wt + ((size_t)g * NPAD + (n0 + nn)) * K + k0 + kq) =
                *(const half8*)&L[nn][kq];
        }
    }
}

// ---------------- fused prep: block 0 = hist+perm, rest = weight transposes ----------------
__global__ __launch_bounds__(256)
void prep(const float* __restrict__ W1, const float* __restrict__ W2,
          const float* __restrict__ W3, f16* __restrict__ W1t,
          f16* __restrict__ W2t, f16* __restrict__ W3t,
          const int* __restrict__ g_idx, int* __restrict__ seg,
          int* __restrict__ perm) {
    __shared__ f16 L[64][72];
    __shared__ int lc[NGEN];
    __shared__ int lb[NGEN + 1];
    int bid = blockIdx.x;
    if (bid == 0) {
        const int t = threadIdx.x;
        if (t < NGEN) lc[t] = 0;
        __syncthreads();
        int gv[BATCH / 256];
        #pragma unroll
        for (int i = 0; i < BATCH / 256; ++i) {
            gv[i] = g_idx[t + i * 256];
            atomicAdd(&lc[gv[i]], 1);
        }
        __syncthreads();
        if (t == 0) {
            int s = 0;
            for (int g = 0; g < NGEN; ++g) { lb[g] = s; s += lc[g]; }
            lb[NGEN] = s;
        }
        __syncthreads();
        if (t <= NGEN) seg[t] = lb[t];
        if (t < NGEN) lc[t] = lb[t];      // reuse as cursors
        __syncthreads();
        #pragma unroll
        for (int i = 0; i < BATCH / 256; ++i) {
            int p = atomicAdd(&lc[gv[i]], 1);
            perm[p] = t + i * 256;
        }
        return;
    }
    --bid;
    if (bid < TB1) { t_tile<NZ, H1, H1>(bid, W1, W1t, L); return; }
    bid -= TB1;
    if (bid < TB2) { t_tile<H1, H2, H2>(bid, W2, W2t, L); return; }
    bid -= TB2;
    t_tile<H2, IMG, IMGP>(bid, W3, W3t, L);
}

// ---------------- 64x64-tile grouped GEMM, counted-vmcnt 3-buffer pipeline ----------------
// Block = (m-tile 64, n-tile 64, gen), 4 waves 2x2, each wave 32x32 (acc[2][2]).
// A and B staged via cp16 (global_load_lds w=16), 4 cp16/wave/tile.
// T4 schedule (never drain vmcnt to 0 in the loop): prologue stages tiles
// 0,1; step k: s_waitcnt vmcnt(4) (tile k's own 4 loads done; tile k+1's 4
// stay in flight ACROSS the barrier) -> raw s_barrier -> stage tile k+2 into
// buf[(k+2)%3] -> ds_read + 8 MFMA on tile k. Buffer reuse safe: buf[(k+2)%3]
// last read at step k-1; all waves passed barrier k after those reads; the
// DMA write lands >=200cy after issue, long after the ~120cy ds_reads.
// Preloaded bias/perm are OLDER than any staged tile, so oldest-first vmcnt
// retirement keeps wait counts valid.
// LDS XOR-swizzle: phys k-quad = logical ^ ((row>>1)&7) -> frag reads 2-way
// bank-aliased (free). B col map: frag nf -> col wn + 2*lm + nf.
// ACT: 0 relu, 1 tanh. SCATTER: 0 -> packed f16 Ch; 1 -> f32 out via perm.
// GATHER: 1 (K=128 only): B tiles both staged up-front; A gathered from f32
// z via perm into raw float4 regs, converted after the wait.
template<int K, int NOUT, int NPADB, int ACT, int SCATTER, int GATHER>
__global__ __launch_bounds__(256)
void gemm(const f16* __restrict__ Ap, const float* __restrict__ Az,
          const f16* __restrict__ Wt, const float* __restrict__ bias,
          f16* __restrict__ Ch, float* __restrict__ Cout,
          const int* __restrict__ seg, const int* __restrict__ perm) {
    constexpr int NT = K / 64;
    constexpr int NBUF = GATHER ? 2 : (NT < 3 ? NT : 3);
    static_assert(!GATHER || NT == 2, "gather path assumes K==128");

    const int g  = blockIdx.z;
    const int s0 = seg[g];
    const int ng = seg[g + 1] - s0;
    const int m0 = blockIdx.x * 64;
    if (m0 >= ng) return;                 // block-uniform early exit
    const int n0 = blockIdx.y * 64;

    __shared__ f16 Bs[NBUF * 64 * 64];
    __shared__ f16 As[GATHER ? 64 : NBUF * 64 * 64];

    const int tid = threadIdx.x, lane = tid & 63, w = tid >> 6;

    // staging geometry: wave w stages rows [w*16, w*16+16) of each tile.
    const f16* gb[2]; const f16* ga[2]; int lbo[2];
    const float* gz[2];
    #pragma unroll
    for (int j = 0; j < 2; ++j) {
        const int r   = w * 16 + j * 8 + (lane >> 3);
        const int swz = ((lane & 7) ^ ((r >> 1) & 7)) * 8;
        gb[j]  = Wt + ((size_t)g * NPADB + n0 + r) * K + swz;
        lbo[j] = (w * 16 + j * 8) * 64;
        if constexpr (GATHER == 0)
            ga[j] = Ap + (size_t)(s0 + m0 + r) * K + swz;
    }

    const int wm = (w & 1) * 32, wn = (w >> 1) * 32;
    const int lm = lane & 15, lq = lane >> 4;

    if constexpr (GATHER != 0) {
        #pragma unroll
        for (int mt = 0; mt < 2; ++mt) {
            const int row = wm + mt * 16 + lm;
            const int pr  = min(s0 + m0 + row, BATCH - 1);  // clamp off perm slack
            gz[mt] = Az + (size_t)perm[pr] * K + lq * 8;
        }
    }

    // bias preload BEFORE staging (older than every staged tile -> vmcnt-safe)
    const int c = n0 + wn + 2 * lm;
    const bool in0 = (!SCATTER) || (c < NOUT);
    const float bv0 = in0 ? bias[(size_t)g * NOUT + c]     : 0.f;
    const float bv1 = in0 ? bias[(size_t)g * NOUT + c + 1] : 0.f;

    floatx4 acc[2][2] = {};

    if constexpr (GATHER == 0) {
        auto stageT = [&](int t, int b) {
            #pragma unroll
            for (int j = 0; j < 2; ++j) cp16(&Bs[b * 4096 + lbo[j]], gb[j] + (size_t)t * 64);
            #pragma unroll
            for (int j = 0; j < 2; ++j) cp16(&As[b * 4096 + lbo[j]], ga[j] + (size_t)t * 64);
        };
        stageT(0, 0);
        __builtin_amdgcn_sched_barrier(0);  // keep tile0 loads older than tile1's
        stageT(1, 1);
        #pragma unroll
        for (int kc = 0; kc < NT; ++kc) {
            if (kc + 1 < NT) asm volatile("s_waitcnt vmcnt(4)" ::: "memory");
            else             asm volatile("s_waitcnt vmcnt(0)" ::: "memory");
            __builtin_amdgcn_sched_barrier(0);
            __builtin_amdgcn_s_barrier();     // all waves' tile-kc loads landed
            __builtin_amdgcn_sched_barrier(0);
            if (kc + 2 < NT) stageT(kc + 2, (kc + 2) % NBUF);
            const int cb = (kc % NBUF) * 4096;
            #pragma unroll
            for (int ks = 0; ks < 2; ++ks) {
                half8 a[2], b[2];
                #pragma unroll
                for (int mt = 0; mt < 2; ++mt) {
                    const int r  = wm + mt * 16 + lm;
                    const int pq = (ks * 4 + lq) ^ ((r >> 1) & 7);
                    a[mt] = *(const half8*)&As[cb + r * 64 + pq * 8];
                }
                #pragma unroll
                for (int nf = 0; nf < 2; ++nf) {
                    const int r  = wn + 2 * lm + nf;
                    const int pq = (ks * 4 + lq) ^ ((r >> 1) & 7);
                    b[nf] = *(const half8*)&Bs[cb + r * 64 + pq * 8];
                }
                #pragma unroll
                for (int mt = 0; mt < 2; ++mt)
                    #pragma unroll
                    for (int nf = 0; nf < 2; ++nf)
                        acc[mt][nf] = __builtin_amdgcn_mfma_f32_16x16x32_f16(
                            a[mt], b[nf], acc[mt][nf], 0, 0, 0);
            }
        }
    } else {
        // K=128: stage everything up front, raw f32 held in regs, one wait each
        float4 rz[2][2][2][2];             // [tile][mt][ks][half] — static-indexed
        auto gatherT = [&](int t) {
            #pragma unroll
            for (int j = 0; j < 2; ++j) cp16(&Bs[t * 4096 + lbo[j]], gb[j] + (size_t)t * 64);
            #pragma unroll
            for (int mt = 0; mt < 2; ++mt)
                #pragma unroll
                for (int ks = 0; ks < 2; ++ks) {
                    rz[t][mt][ks][0] = *(const float4*)(gz[mt] + t * 64 + ks * 32);
                    rz[t][mt][ks][1] = *(const float4*)(gz[mt] + t * 64 + ks * 32 + 4);
                }
        };
        gatherT(0);
        __builtin_amdgcn_sched_barrier(0);  // tile0 loads strictly older
        gatherT(1);
        #pragma unroll
        for (int kc = 0; kc < 2; ++kc) {
            if (kc == 0) asm volatile("s_waitcnt vmcnt(10)" ::: "memory");
            else         asm volatile("s_waitcnt vmcnt(0)" ::: "memory");
            __builtin_amdgcn_sched_barrier(0);
            __builtin_amdgcn_s_barrier();
            __builtin_amdgcn_sched_barrier(0);
            const int cb = kc * 4096;
            #pragma unroll
            for (int ks = 0; ks < 2; ++ks) {
                half8 a[2], b[2];
                #pragma unroll
                for (int mt = 0; mt < 2; ++mt) {
                    const float4 v0 = rz[kc][mt][ks][0];
                    const float4 v1 = rz[kc][mt][ks][1];
                    half8 h;
                    h[0] = (f16)v0.x; h[1] = (f16)v0.y; h[2] = (f16)v0.z; h[3] = (f16)v0.w;
                    h[4] = (f16)v1.x; h[5] = (f16)v1.y; h[6] = (f16)v1.z; h[7] = (f16)v1.w;
                    a[mt] = h;
                }
                #pragma unroll
                for (int nf = 0; nf < 2; ++nf) {
                    const int r  = wn + 2 * lm + nf;
                    const int pq = (ks * 4 + lq) ^ ((r >> 1) & 7);
                    b[nf] = *(const half8*)&Bs[cb + r * 64 + pq * 8];
                }
                #pragma unroll
                for (int mt = 0; mt < 2; ++mt)
                    #pragma unroll
                    for (int nf = 0; nf < 2; ++nf)
                        acc[mt][nf] = __builtin_amdgcn_mfma_f32_16x16x32_f16(
                            a[mt], b[nf], acc[mt][nf], 0, 0, 0);
            }
        }
    }

    // epilogue: C/D row = (lane>>4)*4 + reg; cols c, c+1 (nf=0,1).
    // Even c: pair never straddles NOUT.
    #pragma unroll
    for (int mt = 0; mt < 2; ++mt)
        #pragma unroll
        for (int rr = 0; rr < 4; ++rr) {
            const int gr = m0 + wm + mt * 16 + lq * 4 + rr;
            if (gr >= ng) continue;
            float x0 = acc[mt][0][rr] + bv0;
            float x1 = acc[mt][1][rr] + bv1;
            if (ACT == 0) {
                x0 = fmaxf(x0, 0.f); x1 = fmaxf(x1, 0.f);
            } else {                       // tanh, inf-safe
                const float e0 = __expf(2.f * x0);
                const float e1 = __expf(2.f * x1);
                x0 = 1.f - 2.f / (e0 + 1.f);
                x1 = 1.f - 2.f / (e1 + 1.f);
            }
            if (SCATTER) {
                if (in0) {
                    const size_t orow = (size_t)perm[s0 + gr];
                    *(float2*)&Cout[orow * NOUT + c] = make_float2(x0, x1);
                }
            } else {
                union { uint u; f16 h[2]; } o;
                o.h[0] = (f16)x0; o.h[1] = (f16)x1;
                *(uint*)&Ch[(size_t)(s0 + gr) * NOUT + c] = o.u;
            }
        }
}

extern "C" void kernel_launch(void* const* d_in, const int* in_sizes, int n_in,
                              void* d_out, int out_size, void* d_ws, size_t ws_size,
                              hipStream_t stream) {
    const float* z    = (const float*)d_in[0];
    const int*   gidx = (const int*)  d_in[1];
    const float* W1   = (const float*)d_in[2];
    const float* b1   = (const float*)d_in[3];
    const float* W2   = (const float*)d_in[4];
    const float* b2   = (const float*)d_in[5];
    const float* W3   = (const float*)d_in[6];
    const float* b3   = (const float*)d_in[7];
    float* out = (float*)d_out;

    char* ws = (char*)d_ws;
    size_t off = 0;
    auto alloc = [&](size_t bytes) { size_t o = off; off = (off + bytes + 255) & ~255ULL; return o; };
    int* seg  = (int*)(ws + alloc((size_t)(NGEN + 1) * 4));
    int* perm = (int*)(ws + alloc((size_t)(BATCH + MPAD) * 4));
    f16* h1p = (f16*)(ws + alloc((size_t)(BATCH + MPAD) * H1 * 2));
    f16* h2p = (f16*)(ws + alloc((size_t)(BATCH + MPAD) * H2 * 2));
    f16* W1t = (f16*)(ws + alloc((size_t)NGEN * H1 * NZ * 2));
    f16* W2t = (f16*)(ws + alloc((size_t)NGEN * H2 * H1 * 2));
    f16* W3t = (f16*)(ws + alloc((size_t)NGEN * IMGP * H2 * 2));

    // K1: hist (1 block) co-scheduled with all weight transposes
    prep<<<dim3(1 + TB1 + TB2 + TB3), dim3(256), 0, stream>>>(
        W1, W2, W3, W1t, W2t, W3t, gidx, seg, perm);

    // grid.x = 16 covers any plausible bucket size (<=1024); empty m-tiles
    // exit on the seg[] read. Live blocks ~ 560 / 1120 / 910.
    gemm<NZ, H1, H1, 0, 0, 1><<<dim3(16, H1 / 64, NGEN), dim3(256), 0, stream>>>(
        nullptr, z, W1t, b1, h1p, nullptr, seg, perm);
    gemm<H1, H2, H2, 0, 0, 0><<<dim3(16, H2 / 64, NGEN), dim3(256), 0, stream>>>(
        h1p, nullptr, W2t, b2, h2p, nullptr, seg, perm);
    gemm<H2, IMG, IMGP, 1, 1, 0><<<dim3(16, IMGP / 64, NGEN), dim3(256), 0, stream>>>(
        h2p, nullptr, W3t, b3, nullptr, out, seg, perm);
}

// Round 5
// 155.429 us; speedup vs baseline: 1.6300x; 1.2023x over previous
//
#include <hip/hip_runtime.h>
#include <math.h>

#define NZ    128
#define H1    512
#define H2    1024
#define IMG   784
#define IMGP  896     // layer-3 N padded to 7*128
#define BATCH 4096
#define NGEN  10
#define MPAD  128     // packed-row slack so tail tiles can stage past ng

typedef _Float16 f16;
typedef __attribute__((ext_vector_type(8))) _Float16 half8;
typedef __attribute__((ext_vector_type(4))) float floatx4;

// transpose tile counts (64x64 tiles) for the fused prep kernel
#define TB1 ((NZ / 64) * (H1 / 64) * NGEN)    // 160
#define TB2 ((H1 / 64) * (H2 / 64) * NGEN)    // 1280
#define TB3 ((H2 / 64) * (IMGP / 64) * NGEN)  // 2240

__device__ __forceinline__ void cp16(void* l, const void* g) {
    __builtin_amdgcn_global_load_lds((const __attribute__((address_space(1))) void*)g,
                                     (__attribute__((address_space(3))) void*)l, 16, 0, 0);
}

// ---------------- transpose one 64x64 tile: W [g][K][N] f32 -> Wt [g][NPAD][K] f16 ----------------
template<int K, int N, int NPAD>
__device__ __forceinline__ void t_tile(int idx, const float* __restrict__ W,
                                       f16* __restrict__ Wt, f16 (*L)[72]) {
    constexpr int KT = K / 64, NT = NPAD / 64;
    const int g  = idx / (KT * NT);
    const int r2 = idx % (KT * NT);
    const int k0 = (r2 % KT) * 64;
    const int n0 = (r2 / KT) * 64;
    const int t = threadIdx.x;
    {
        const int kk0 = t >> 4;            // 0..15
        const int nq  = (t & 15) * 4;      // 0..60
        #pragma unroll
        for (int it = 0; it < 4; ++it) {
            const int kk = kk0 + it * 16;
            float4 v = make_float4(0.f, 0.f, 0.f, 0.f);
            if (n0 + nq < N)               // N % 4 == 0: quads never straddle
                v = *(const float4*)(W + ((size_t)g * K + (k0 + kk)) * N + n0 + nq);
            L[nq + 0][kk] = (f16)v.x;
            L[nq + 1][kk] = (f16)v.y;
            L[nq + 2][kk] = (f16)v.z;
            L[nq + 3][kk] = (f16)v.w;
        }
    }
    __syncthreads();
    {
        const int nn0 = t >> 3;            // 0..31
        const int kq  = (t & 7) * 8;       // 0..56
        #pragma unroll
        for (int it = 0; it < 2; ++it) {
            const int nn = nn0 + it * 32;
            *(half8*)(Wt + ((size_t)g * NPAD + (n0 + nn)) * K + k0 + kq) =
                *(const half8*)&L[nn][kq];
        }
    }
}

// ---------------- fused prep: block 0 = hist+perm, rest = weight transposes ----------------
__global__ __launch_bounds__(256)
void prep(const float* __restrict__ W1, const float* __restrict__ W2,
          const float* __restrict__ W3, f16* __restrict__ W1t,
          f16* __restrict__ W2t, f16* __restrict__ W3t,
          const int* __restrict__ g_idx, int* __restrict__ seg,
          int* __restrict__ perm) {
    __shared__ f16 L[64][72];
    __shared__ int lc[NGEN];
    __shared__ int lb[NGEN + 1];
    int bid = blockIdx.x;
    if (bid == 0) {
        const int t = threadIdx.x;
        if (t < NGEN) lc[t] = 0;
        __syncthreads();
        int gv[BATCH / 256];
        #pragma unroll
        for (int i = 0; i < BATCH / 256; ++i) {
            gv[i] = g_idx[t + i * 256];
            atomicAdd(&lc[gv[i]], 1);
        }
        __syncthreads();
        if (t == 0) {
            int s = 0;
            for (int g = 0; g < NGEN; ++g) { lb[g] = s; s += lc[g]; }
            lb[NGEN] = s;
        }
        __syncthreads();
        if (t <= NGEN) seg[t] = lb[t];
        if (t < NGEN) lc[t] = lb[t];      // reuse as cursors
        __syncthreads();
        #pragma unroll
        for (int i = 0; i < BATCH / 256; ++i) {
            int p = atomicAdd(&lc[gv[i]], 1);
            perm[p] = t + i * 256;
        }
        return;
    }
    --bid;
    if (bid < TB1) { t_tile<NZ, H1, H1>(bid, W1, W1t, L); return; }
    bid -= TB1;
    if (bid < TB2) { t_tile<H1, H2, H2>(bid, W2, W2t, L); return; }
    bid -= TB2;
    t_tile<H2, IMG, IMGP>(bid, W3, W3t, L);
}

// ---------------- 128x128-tile grouped GEMM, counted-vmcnt double-buffer ----------------
// Block = one (m-tile 128, n-tile 128, gen); 4 waves 2x2, each wave 64x64
// (acc[4][4]). Staging traffic per FLOP is 4x lower than the 64x64 tile:
// G3 falls 233 MB -> 72 MB of L2/HBM tile traffic (the measured r4
// bottleneck: 5.7 TB/s staging saturation).
// Gen-chunked XCD swizzle: 1D grid, L = (H&7)*CHUNK + H/8 (NWG % 8 == 0)
// -> each XCD gets contiguous logical blocks => ~1.25 gens/XCD; per-gen
// A+B working set (~2.5 MB) fits the 4 MB per-XCD L2, and producer/consumer
// kernels touch the same gens on the same XCDs.
// Per K-step: vmcnt(8) [tile k landed, tile k+1's 8 cp16 stay in flight
// across the barrier] -> s_barrier -> 16 ds_read_b128 frags -> lgkmcnt(0)
// -> s_barrier#2 [all waves' reads done -> buffer free] -> stage tile k+2
// into buf[k&1] -> 32 MFMA. No vmcnt(0) drain inside the loop.
// LDS XOR-swizzle: phys k-quad = logical ^ ((row>>1)&7) (2-way = free).
// B col map: frag nf -> col wn + (nf>>1)*32 + 2*lm + (nf&1).
// ACT: 0 relu, 1 tanh. SCATTER: 0 -> packed f16 Ch; 1 -> f32 out via perm.
template<int K, int NOUT, int NPADB, int NM, int NN, int ACT, int SCATTER>
__global__ __launch_bounds__(256)
void gemm128(const f16* __restrict__ Ap, const f16* __restrict__ Wt,
             const float* __restrict__ bias, f16* __restrict__ Ch,
             float* __restrict__ Cout, const int* __restrict__ seg,
             const int* __restrict__ perm) {
    constexpr int NT  = K / 64;
    constexpr int NWG = NM * NN * NGEN;
    static_assert(NWG % 8 == 0, "gen-chunk swizzle needs NWG % 8 == 0");
    static_assert(NT >= 2, "pipeline assumes K >= 128");
    constexpr int CHUNK = NWG / 8;

    const int H = blockIdx.x;
    const int L = (H & 7) * CHUNK + (H >> 3);   // bijective: NWG % 8 == 0
    const int g   = L / (NM * NN);
    const int rem = L - g * (NM * NN);
    const int nt  = rem / NM;
    const int mt0 = rem - nt * NM;              // m-fastest within a chunk
    const int s0 = seg[g];
    const int ng = seg[g + 1] - s0;
    const int m0 = mt0 * 128;
    if (m0 >= ng) return;                       // block-uniform early exit
    const int n0 = nt * 128;

    __shared__ f16 As[2 * 128 * 64];            // 32 KB
    __shared__ f16 Bs[2 * 128 * 64];            // 32 KB

    const int tid = threadIdx.x, lane = tid & 63, w = tid >> 6;

    // staging: wave w stages rows [w*32, w*32+32) of A and B tiles, 4 cp16 each.
    const f16* ga[4]; const f16* gb[4]; int lo[4];
    #pragma unroll
    for (int j = 0; j < 4; ++j) {
        const int r   = w * 32 + j * 8 + (lane >> 3);
        const int swz = ((lane & 7) ^ ((r >> 1) & 7)) * 8;
        ga[j] = Ap + (size_t)(s0 + m0 + r) * K + swz;
        gb[j] = Wt + ((size_t)g * NPADB + n0 + r) * K + swz;
        lo[j] = (w * 32 + j * 8) * 64;          // wave-uniform LDS base
    }

    const int wm = (w & 1) * 64, wn = (w >> 1) * 64;
    const int lm = lane & 15, lq = lane >> 4;

    // bias preload (older than all staged tiles -> vmcnt counting stays valid)
    const int c = n0 + wn + 2 * lm;
    const bool in0 = (!SCATTER) || (c < NOUT);
    const bool in1 = (!SCATTER) || (c + 32 < NOUT);
    const float* bg = bias + (size_t)g * NOUT;
    const float bv0 = in0 ? bg[c]      : 0.f;
    const float bv1 = in0 ? bg[c + 1]  : 0.f;
    const float bv2 = in1 ? bg[c + 32] : 0.f;
    const float bv3 = in1 ? bg[c + 33] : 0.f;

    floatx4 acc[4][4] = {};

    auto stage = [&](int t, int b) {
        #pragma unroll
        for (int j = 0; j < 4; ++j) cp16(&As[b * 8192 + lo[j]], ga[j] + (size_t)t * 64);
        #pragma unroll
        for (int j = 0; j < 4; ++j) cp16(&Bs[b * 8192 + lo[j]], gb[j] + (size_t)t * 64);
    };
    stage(0, 0);
    __builtin_amdgcn_sched_barrier(0);          // tile0's 8 loads strictly older
    stage(1, 1);

    for (int kc = 0; kc < NT; ++kc) {
        if (kc + 1 < NT) asm volatile("s_waitcnt vmcnt(8)" ::: "memory");
        else             asm volatile("s_waitcnt vmcnt(0)" ::: "memory");
        __builtin_amdgcn_sched_barrier(0);
        __builtin_amdgcn_s_barrier();           // tile kc visible to all waves
        __builtin_amdgcn_sched_barrier(0);

        const int cb = (kc & 1) * 8192;
        half8 a[2][4], b[2][4];
        #pragma unroll
        for (int ks = 0; ks < 2; ++ks) {
            #pragma unroll
            for (int mt = 0; mt < 4; ++mt) {
                const int r  = wm + mt * 16 + lm;
                const int pq = (ks * 4 + lq) ^ ((r >> 1) & 7);
                a[ks][mt] = *(const half8*)&As[cb + r * 64 + pq * 8];
            }
            #pragma unroll
            for (int nf = 0; nf < 4; ++nf) {
                const int r  = wn + (nf >> 1) * 32 + 2 * lm + (nf & 1);
                const int pq = (ks * 4 + lq) ^ ((r >> 1) & 7);
                b[ks][nf] = *(const half8*)&Bs[cb + r * 64 + pq * 8];
            }
        }
        asm volatile("s_waitcnt lgkmcnt(0)" ::: "memory");  // my reads complete
        __builtin_amdgcn_sched_barrier(0);
        if (kc + 2 < NT) {
            __builtin_amdgcn_s_barrier();       // ALL waves' reads done: buf free
            __builtin_amdgcn_sched_barrier(0);
            stage(kc + 2, kc & 1);              // overwrite just-freed buffer
        }
        #pragma unroll
        for (int ks = 0; ks < 2; ++ks)
            #pragma unroll
            for (int mt = 0; mt < 4; ++mt)
                #pragma unroll
                for (int nf = 0; nf < 4; ++nf)
                    acc[mt][nf] = __builtin_amdgcn_mfma_f32_16x16x32_f16(
                        a[ks][mt], b[ks][nf], acc[mt][nf], 0, 0, 0);
    }

    // epilogue: C/D row = (lane>>4)*4 + reg; col pairs (c,c+1),(c+32,c+33).
    #pragma unroll
    for (int mt = 0; mt < 4; ++mt)
        #pragma unroll
        for (int rr = 0; rr < 4; ++rr) {
            const int gr = m0 + wm + mt * 16 + lq * 4 + rr;
            if (gr >= ng) continue;
            float x0 = acc[mt][0][rr] + bv0;
            float x1 = acc[mt][1][rr] + bv1;
            float x2 = acc[mt][2][rr] + bv2;
            float x3 = acc[mt][3][rr] + bv3;
            if (ACT == 0) {
                x0 = fmaxf(x0, 0.f); x1 = fmaxf(x1, 0.f);
                x2 = fmaxf(x2, 0.f); x3 = fmaxf(x3, 0.f);
            } else {                            // tanh, inf-safe
                const float e0 = __expf(2.f * x0);
                const float e1 = __expf(2.f * x1);
                const float e2 = __expf(2.f * x2);
                const float e3 = __expf(2.f * x3);
                x0 = 1.f - 2.f / (e0 + 1.f);
                x1 = 1.f - 2.f / (e1 + 1.f);
                x2 = 1.f - 2.f / (e2 + 1.f);
                x3 = 1.f - 2.f / (e3 + 1.f);
            }
            if (SCATTER) {
                const size_t orow = (size_t)perm[s0 + gr];
                if (in0) *(float2*)&Cout[orow * NOUT + c]      = make_float2(x0, x1);
                if (in1) *(float2*)&Cout[orow * NOUT + c + 32] = make_float2(x2, x3);
            } else {
                union { uint u; f16 h[2]; } o0, o1;
                o0.h[0] = (f16)x0; o0.h[1] = (f16)x1;
                o1.h[0] = (f16)x2; o1.h[1] = (f16)x3;
                *(uint*)&Ch[(size_t)(s0 + gr) * NOUT + c]      = o0.u;
                *(uint*)&Ch[(size_t)(s0 + gr) * NOUT + c + 32] = o1.u;
            }
        }
}

// ---------------- layer 1: K=128, both K-tiles staged up-front ----------------
// A gathered from f32 z via perm (in-register convert, swizzled ds_write);
// B via cp16. One __syncthreads total, then 2 K-steps of pure LDS+MFMA.
__global__ __launch_bounds__(256)
void gemm_l1(const float* __restrict__ Az, const f16* __restrict__ Wt,
             const float* __restrict__ bias, f16* __restrict__ Ch,
             const int* __restrict__ seg, const int* __restrict__ perm) {
    constexpr int K = NZ, NOUT = H1, NPADB = H1, NM = 8, NN = 4;
    constexpr int NWG = NM * NN * NGEN, CHUNK = NWG / 8;
    const int H = blockIdx.x;
    const int L = (H & 7) * CHUNK + (H >> 3);
    const int g   = L / (NM * NN);
    const int rem = L - g * (NM * NN);
    const int nt  = rem / NM;
    const int mt0 = rem - nt * NM;
    const int s0 = seg[g];
    const int ng = seg[g + 1] - s0;
    const int m0 = mt0 * 128;
    if (m0 >= ng) return;
    const int n0 = nt * 128;

    __shared__ f16 As[2 * 8192];
    __shared__ f16 Bs[2 * 8192];
    const int tid = threadIdx.x, lane = tid & 63, w = tid >> 6;

    // B: both K-tiles via cp16
    #pragma unroll
    for (int j = 0; j < 4; ++j) {
        const int r   = w * 32 + j * 8 + (lane >> 3);
        const int swz = ((lane & 7) ^ ((r >> 1) & 7)) * 8;
        const f16* gbj = Wt + ((size_t)g * NPADB + n0 + r) * K + swz;
        const int  loj = (w * 32 + j * 8) * 64;
        cp16(&Bs[loj],        gbj);
        cp16(&Bs[8192 + loj], gbj + 64);
    }
    // A: gather z rows via perm, convert, swizzled ds_write (8 lanes/row)
    int prow[4];
    #pragma unroll
    for (int p = 0; p < 4; ++p) {
        const int r = w * 32 + p * 8 + (lane >> 3);
        prow[p] = perm[min(s0 + m0 + r, BATCH - 1)];   // clamp off perm slack
    }
    #pragma unroll
    for (int t = 0; t < 2; ++t)
        #pragma unroll
        for (int p = 0; p < 4; ++p) {
            const int r = w * 32 + p * 8 + (lane >> 3);
            const float* src = Az + (size_t)prow[p] * K + t * 64 + (lane & 7) * 8;
            const float4 v0 = *(const float4*)src;
            const float4 v1 = *(const float4*)(src + 4);
            half8 h;
            h[0] = (f16)v0.x; h[1] = (f16)v0.y; h[2] = (f16)v0.z; h[3] = (f16)v0.w;
            h[4] = (f16)v1.x; h[5] = (f16)v1.y; h[6] = (f16)v1.z; h[7] = (f16)v1.w;
            const int pq = (lane & 7) ^ ((r >> 1) & 7);
            *(half8*)&As[t * 8192 + r * 64 + pq * 8] = h;
        }

    const int wm = (w & 1) * 64, wn = (w >> 1) * 64;
    const int lm = lane & 15, lq = lane >> 4;
    const int c = n0 + wn + 2 * lm;
    const float* bg = bias + (size_t)g * NOUT;
    const float bv0 = bg[c], bv1 = bg[c + 1], bv2 = bg[c + 32], bv3 = bg[c + 33];

    __syncthreads();                           // drains cp16 + ds_write

    floatx4 acc[4][4] = {};
    #pragma unroll
    for (int kc = 0; kc < 2; ++kc) {
        const int cb = kc * 8192;
        half8 a[2][4], b[2][4];
        #pragma unroll
        for (int ks = 0; ks < 2; ++ks) {
            #pragma unroll
            for (int mt = 0; mt < 4; ++mt) {
                const int r  = wm + mt * 16 + lm;
                const int pq = (ks * 4 + lq) ^ ((r >> 1) & 7);
                a[ks][mt] = *(const half8*)&As[cb + r * 64 + pq * 8];
            }
            #pragma unroll
            for (int nf = 0; nf < 4; ++nf) {
                const int r  = wn + (nf >> 1) * 32 + 2 * lm + (nf & 1);
                const int pq = (ks * 4 + lq) ^ ((r >> 1) & 7);
                b[ks][nf] = *(const half8*)&Bs[cb + r * 64 + pq * 8];
            }
        }
        #pragma unroll
        for (int ks = 0; ks < 2; ++ks)
            #pragma unroll
            for (int mt = 0; mt < 4; ++mt)
                #pragma unroll
                for (int nf = 0; nf < 4; ++nf)
                    acc[mt][nf] = __builtin_amdgcn_mfma_f32_16x16x32_f16(
                        a[ks][mt], b[ks][nf], acc[mt][nf], 0, 0, 0);
    }

    #pragma unroll
    for (int mt = 0; mt < 4; ++mt)
        #pragma unroll
        for (int rr = 0; rr < 4; ++rr) {
            const int gr = m0 + wm + mt * 16 + lq * 4 + rr;
            if (gr >= ng) continue;
            float x0 = fmaxf(acc[mt][0][rr] + bv0, 0.f);
            float x1 = fmaxf(acc[mt][1][rr] + bv1, 0.f);
            float x2 = fmaxf(acc[mt][2][rr] + bv2, 0.f);
            float x3 = fmaxf(acc[mt][3][rr] + bv3, 0.f);
            union { uint u; f16 h[2]; } o0, o1;
            o0.h[0] = (f16)x0; o0.h[1] = (f16)x1;
            o1.h[0] = (f16)x2; o1.h[1] = (f16)x3;
            *(uint*)&Ch[(size_t)(s0 + gr) * NOUT + c]      = o0.u;
            *(uint*)&Ch[(size_t)(s0 + gr) * NOUT + c + 32] = o1.u;
        }
}

extern "C" void kernel_launch(void* const* d_in, const int* in_sizes, int n_in,
                              void* d_out, int out_size, void* d_ws, size_t ws_size,
                              hipStream_t stream) {
    const float* z    = (const float*)d_in[0];
    const int*   gidx = (const int*)  d_in[1];
    const float* W1   = (const float*)d_in[2];
    const float* b1   = (const float*)d_in[3];
    const float* W2   = (const float*)d_in[4];
    const float* b2   = (const float*)d_in[5];
    const float* W3   = (const float*)d_in[6];
    const float* b3   = (const float*)d_in[7];
    float* out = (float*)d_out;

    char* ws = (char*)d_ws;
    size_t off = 0;
    auto alloc = [&](size_t bytes) { size_t o = off; off = (off + bytes + 255) & ~255ULL; return o; };
    int* seg  = (int*)(ws + alloc((size_t)(NGEN + 1) * 4));
    int* perm = (int*)(ws + alloc((size_t)(BATCH + MPAD) * 4));
    f16* h1p = (f16*)(ws + alloc((size_t)(BATCH + MPAD) * H1 * 2));
    f16* h2p = (f16*)(ws + alloc((size_t)(BATCH + MPAD) * H2 * 2));
    f16* W1t = (f16*)(ws + alloc((size_t)NGEN * H1 * NZ * 2));
    f16* W2t = (f16*)(ws + alloc((size_t)NGEN * H2 * H1 * 2));
    f16* W3t = (f16*)(ws + alloc((size_t)NGEN * IMGP * H2 * 2));

    // K1: hist (1 block) co-scheduled with all weight transposes
    prep<<<dim3(1 + TB1 + TB2 + TB3), dim3(256), 0, stream>>>(
        W1, W2, W3, W1t, W2t, W3t, gidx, seg, perm);

    // 1D grids, gen-chunked XCD swizzle inside the kernels.
    // NM=8 covers up to 1024 rows/gen; dead m-tiles exit on the seg[] read.
    gemm_l1<<<dim3(8 * 4 * NGEN), dim3(256), 0, stream>>>(
        z, W1t, b1, h1p, seg, perm);
    gemm128<H1, H2, H2, 8, 8, 0, 0><<<dim3(8 * 8 * NGEN), dim3(256), 0, stream>>>(
        h1p, W2t, b2, h2p, nullptr, seg, perm);
    gemm128<H2, IMG, IMGP, 8, 7, 1, 1><<<dim3(8 * 7 * NGEN), dim3(256), 0, stream>>>(
        h2p, W3t, b3, nullptr, out, seg, perm);
}